// Round 6
// baseline (37.179 us; speedup 1.0000x reference)
//
#include <hip/hip_runtime.h>

// Problem geometry (fixed by reference setup_inputs)
#define B  4
#define D  48
#define H  128
#define W  240
#define H4 512   // 4*H
#define W4 960   // 4*W
#define TS 8     // coarse tile side; grid = (W/TS)*(H/TS)*B = 30*16*4 = 1920 blocks
#define DSPLIT 2
#define DPART  (D / DSPLIT)
#define HS (TS + 2)        // halo side = 10

// Fused per-block kernel: phase A computes the 10x10 halo'd top-2 soft-argmax
// disp into LDS (2 threads per pixel, shfl-merged — the proven R4 reduction),
// block barrier, phase B does 3x3 unfold + 4x nearest upsample + spg-weighted
// sum, *4. TS=8 gives 1920 blocks (7.5 waves/SIMD) so phases overlap chip-wide.
__global__ void __launch_bounds__(256)
fused_tile_kernel(const float* __restrict__ cost, const float* __restrict__ spg,
                  float* __restrict__ out) {
    __shared__ float sd[HS][HS + 1];

    int blk = blockIdx.x;
    int txt = blk % (W / TS);
    int rem = blk / (W / TS);
    int tyt = rem % (H / TS);
    int b   = rem / (H / TS);
    int x0  = txt * TS - 1;            // halo origin (coarse coords)
    int y0  = tyt * TS - 1;

    // ---- Phase A: 100 halo pixels x 2 d-halves = 200 threads ----
    int i = threadIdx.x;
    if (i < HS * HS * DSPLIT) {
        int pix  = i >> 1;
        int half = i & 1;
        int hy   = pix / HS;
        int hx   = pix - hy * HS;
        int y    = y0 + hy;
        int x    = x0 + hx;
        float dres = 0.0f;             // zero-pad outside image
        if ((unsigned)x < W && (unsigned)y < H) {
            const float* p = cost + (size_t)b * (D * H * W)
                                  + (size_t)(half * DPART) * (H * W) + y * W + x;
            float v[DPART];
            #pragma unroll
            for (int d = 0; d < DPART; ++d) v[d] = p[(size_t)d * (H * W)];

            float v1 = -INFINITY, v2 = -INFINITY;
            int   i1 = 0,          i2 = 0;
            const int d0 = half * DPART;
            #pragma unroll
            for (int d = 0; d < DPART; ++d) {
                float xv = v[d];
                if (xv > v1)      { v2 = v1; i2 = i1; v1 = xv; i1 = d0 + d; }
                else if (xv > v2) { v2 = xv; i2 = d0 + d; }
            }

            // merge partner's top-2 (partner = lane^1, same pixel, other half)
            float pv1 = __shfl_xor(v1, 1);
            int   pi1 = __shfl_xor(i1, 1);
            float pv2 = __shfl_xor(v2, 1);
            int   pi2 = __shfl_xor(i2, 1);

            float av1, av2, bv1, bv2; int ai1, ai2, bi1, bi2;
            if (half == 0) { av1=v1;  ai1=i1;  av2=v2;  ai2=i2;  bv1=pv1; bi1=pi1; bv2=pv2; bi2=pi2; }
            else           { av1=pv1; ai1=pi1; av2=pv2; ai2=pi2; bv1=v1;  bi1=i1;  bv2=v2;  bi2=i2; }

            float t1v, t2v; int t1i, t2i;
            if (bv1 > av1) {           // top1 from high-index half
                t1v = bv1; t1i = bi1;
                if (av1 >= bv2) { t2v = av1; t2i = ai1; } else { t2v = bv2; t2i = bi2; }
            } else {                   // top1 from low half (ties -> low index)
                t1v = av1; t1i = ai1;
                if (av2 >= bv1) { t2v = av2; t2i = ai2; } else { t2v = bv1; t2i = bi1; }
            }

            float e = expf(t2v - t1v);
            dres = ((float)t1i + (float)t2i * e) / (1.0f + e);
        }
        if (half == 0) sd[hy][hx] = dres;
    }
    __syncthreads();

    // ---- Phase B: 256 threads = 32 fine rows x 8 float4 groups ----
    int t   = threadIdx.x;
    int fx4 = t & (TS - 1);            // 0..7  (float4 group == coarse x)
    int fy  = t >> 3;                  // 0..31 (fine row within tile)
    int cyl = fy >> 2;                 // local coarse y 0..7
    int Y   = tyt * TS * 4 + fy;       // global fine row
    int X4  = txt * TS + fx4;          // global float4 column index

    float dv[9];
    #pragma unroll
    for (int dy = 0; dy < 3; ++dy)
        #pragma unroll
        for (int dx = 0; dx < 3; ++dx)
            dv[dy * 3 + dx] = sd[cyl + dy][fx4 + dx];

    const float* sp = spg + ((size_t)(b * 9) * H4 + Y) * W4 + X4 * 4;
    float4 acc = make_float4(0.f, 0.f, 0.f, 0.f);
    #pragma unroll
    for (int k = 0; k < 9; ++k) {
        float4 s = *reinterpret_cast<const float4*>(sp + (size_t)k * (H4 * W4));
        float  d = dv[k];
        acc.x += d * s.x; acc.y += d * s.y; acc.z += d * s.z; acc.w += d * s.w;
    }
    acc.x *= 4.f; acc.y *= 4.f; acc.z *= 4.f; acc.w *= 4.f;

    *reinterpret_cast<float4*>(out + ((size_t)b * H4 + Y) * W4 + X4 * 4) = acc;
}

extern "C" void kernel_launch(void* const* d_in, const int* in_sizes, int n_in,
                              void* d_out, int out_size, void* d_ws, size_t ws_size,
                              hipStream_t stream) {
    const float* cost = (const float*)d_in[0];   // [B,1,D,H,W]
    const float* spg  = (const float*)d_in[1];   // [B,9,H4,W4]
    float* outp = (float*)d_out;                 // [B,H4,W4]

    const int nblk = (W / TS) * (H / TS) * B;    // 1920
    fused_tile_kernel<<<nblk, 256, 0, stream>>>(cost, spg, outp);
}